// Round 1
// baseline (292.955 us; speedup 1.0000x reference)
//
#include <hip/hip_runtime.h>
#include <hip/hip_bf16.h>

// Problem constants
#define BDIM 8
#define NNODE 2048
#define CIN 256
#define NEDGE 32768
#define NHEAD 8
#define COUT 64
#define HC 512            // NHEAD * COUT
#define BN_TOT 16384      // BDIM * NNODE
#define NEG_SLOPE 0.2f

// ---------------------------------------------------------------------------
// Kernel 1: xt = x @ W_lin   [16384,256] x [256,512] -> [16384,512], fp32
// BM=64, BN=64, BK=16, 256 threads, 4x4 per-thread microtile.
// ---------------------------------------------------------------------------
__global__ __launch_bounds__(256) void gemm_f32(const float* __restrict__ A,
                                                const float* __restrict__ Bm,
                                                float* __restrict__ Cm) {
    const int K = CIN, N = HC;
    __shared__ float As[16][68];   // stride 68: float4-aligned rows, conflict-light stores
    __shared__ float Bs[16][64];

    const int tid  = threadIdx.x;
    const int row0 = blockIdx.y * 64;
    const int col0 = blockIdx.x * 64;
    const int tx = tid & 15;       // col group
    const int ty = tid >> 4;       // row group

    const int am = tid >> 2;           // 0..63 (A row within tile)
    const int ak = (tid & 3) * 4;      // 0,4,8,12 (A col within tile)
    const int bk = tid >> 4;           // 0..15 (B row within tile)
    const int bn = (tid & 15) * 4;     // 0..60 (B col within tile)

    float acc[4][4] = {};

    for (int k0 = 0; k0 < K; k0 += 16) {
        float4 a4 = *(const float4*)&A[(row0 + am) * K + k0 + ak];
        float4 b4 = *(const float4*)&Bm[(k0 + bk) * N + col0 + bn];
        __syncthreads();
        As[ak + 0][am] = a4.x;
        As[ak + 1][am] = a4.y;
        As[ak + 2][am] = a4.z;
        As[ak + 3][am] = a4.w;
        *(float4*)&Bs[bk][bn] = b4;
        __syncthreads();
#pragma unroll
        for (int k = 0; k < 16; ++k) {
            float4 av = *(const float4*)&As[k][ty * 4];
            float4 bv = *(const float4*)&Bs[k][tx * 4];
            float a[4] = {av.x, av.y, av.z, av.w};
            float b[4] = {bv.x, bv.y, bv.z, bv.w};
#pragma unroll
            for (int i = 0; i < 4; ++i)
#pragma unroll
                for (int j = 0; j < 4; ++j) acc[i][j] += a[i] * b[j];
        }
    }
#pragma unroll
    for (int i = 0; i < 4; ++i) {
        float4 v = {acc[i][0], acc[i][1], acc[i][2], acc[i][3]};
        *(float4*)&Cm[(row0 + ty * 4 + i) * N + col0 + tx * 4] = v;
    }
}

// ---------------------------------------------------------------------------
// Kernel 2: per-node attention scores
//   s_src[n,h] = dot(xt[n,h,:], att_src[h,:]) ; same for dst.
// Block = 256 threads = 4 waves, each wave handles one node.
// Lane l covers channels [8l, 8l+8); head = l/8; 8-lane shuffle reduce.
// ---------------------------------------------------------------------------
__global__ __launch_bounds__(256) void att_scores(const float* __restrict__ xt,
                                                  const float* __restrict__ att_src,
                                                  const float* __restrict__ att_dst,
                                                  float* __restrict__ ssrc,
                                                  float* __restrict__ sdst) {
    const int n = blockIdx.x * 4 + (threadIdx.x >> 6);
    const int l = threadIdx.x & 63;

    const float4* p = (const float4*)&xt[n * HC + l * 8];
    float4 v0 = p[0], v1 = p[1];
    const float4* as = (const float4*)&att_src[l * 8];
    float4 a0 = as[0], a1 = as[1];
    const float4* ad = (const float4*)&att_dst[l * 8];
    float4 b0 = ad[0], b1 = ad[1];

    float ps = v0.x * a0.x + v0.y * a0.y + v0.z * a0.z + v0.w * a0.w +
               v1.x * a1.x + v1.y * a1.y + v1.z * a1.z + v1.w * a1.w;
    float pd = v0.x * b0.x + v0.y * b0.y + v0.z * b0.z + v0.w * b0.w +
               v1.x * b1.x + v1.y * b1.y + v1.z * b1.z + v1.w * b1.w;

    ps += __shfl_xor(ps, 4); ps += __shfl_xor(ps, 2); ps += __shfl_xor(ps, 1);
    pd += __shfl_xor(pd, 4); pd += __shfl_xor(pd, 2); pd += __shfl_xor(pd, 1);

    if ((l & 7) == 0) {
        ssrc[n * NHEAD + (l >> 3)] = ps;
        sdst[n * NHEAD + (l >> 3)] = pd;
    }
}

// ---------------------------------------------------------------------------
// CSR build (dst-major). Edge list is shared across batches, so counts and
// prefix only need N=2048 entries; per-batch rowptr is a constant offset.
// Self-loops are NOT materialized (handled analytically in aggregation).
// ---------------------------------------------------------------------------
__global__ void count_edges(const int* __restrict__ ei, int* __restrict__ cnt) {
    int t = blockIdx.x * 256 + threadIdx.x;   // t < NEDGE
    atomicAdd(&cnt[ei[NEDGE + t]], 1);
}

__global__ __launch_bounds__(256) void scan_rowptr(const int* __restrict__ cnt,
                                                   int* __restrict__ rowptr,
                                                   int* __restrict__ widx) {
    __shared__ int sums[256];
    const int t = threadIdx.x;
    int v[8];
    int tot = 0;
#pragma unroll
    for (int i = 0; i < 8; ++i) { v[i] = cnt[t * 8 + i]; tot += v[i]; }
    sums[t] = tot;
    __syncthreads();
    for (int off = 1; off < 256; off <<= 1) {
        int x = (t >= off) ? sums[t - off] : 0;
        __syncthreads();
        sums[t] += x;
        __syncthreads();
    }
    int run = sums[t] - tot;  // exclusive prefix of this thread's chunk
    int base[8];
#pragma unroll
    for (int i = 0; i < 8; ++i) { base[i] = run; run += v[i]; }
#pragma unroll
    for (int b = 0; b < BDIM; ++b) {
#pragma unroll
        for (int i = 0; i < 8; ++i) {
            int n = t * 8 + i;
            int val = b * NEDGE + base[i];
            rowptr[b * NNODE + n] = val;
            widx[b * NNODE + n] = val;
        }
    }
}

__global__ void scatter_edges(const int* __restrict__ ei, int* __restrict__ widx,
                              int* __restrict__ col) {
    int t = blockIdx.x * 256 + threadIdx.x;   // t < BDIM*NEDGE
    int b = t >> 15;                          // t / NEDGE
    int e = t & (NEDGE - 1);
    int s = ei[e];
    int d = ei[NEDGE + e];
    int p = atomicAdd(&widx[b * NNODE + d], 1);
    col[p] = b * NNODE + s;
}

// ---------------------------------------------------------------------------
// Kernel 3: per-node softmax + aggregation.
// One block per node; 8 waves = 8 heads. Wave does:
//   phase 1: max over incoming-edge logits (edge-parallel across lanes)
//   phase 2: exp-sum
//   phase 3: channel-parallel weighted accumulation (lane = channel),
//            coalesced 256B reads of xt[src, head, :].
// ---------------------------------------------------------------------------
__global__ __launch_bounds__(512) void aggregate(const float* __restrict__ xt,
                                                 const float* __restrict__ ssrc,
                                                 const float* __restrict__ sdst,
                                                 const int* __restrict__ cnt,
                                                 const int* __restrict__ rowptr,
                                                 const int* __restrict__ col,
                                                 const float* __restrict__ bias,
                                                 float* __restrict__ out) {
    const int i = blockIdx.x;               // global node id
    const int h = threadIdx.x >> 6;         // head
    const int lane = threadIdx.x & 63;
    const int n = i & (NNODE - 1);          // node within batch
    const int deg = cnt[n];
    const int start = rowptr[i];

    const float sd = sdst[i * NHEAD + h];
    float self_raw = ssrc[i * NHEAD + h] + sd;
    float self_logit = self_raw >= 0.f ? self_raw : NEG_SLOPE * self_raw;

    // phase 1: running max
    float m = self_logit;
    for (int e = lane; e < deg; e += 64) {
        int j = col[start + e];
        float v = ssrc[j * NHEAD + h] + sd;
        v = v >= 0.f ? v : NEG_SLOPE * v;
        m = fmaxf(m, v);
    }
#pragma unroll
    for (int off = 32; off; off >>= 1) m = fmaxf(m, __shfl_xor(m, off));

    // phase 2: exp-sum
    float ssum = (lane == 0) ? __expf(self_logit - m) : 0.f;
    for (int e = lane; e < deg; e += 64) {
        int j = col[start + e];
        float v = ssrc[j * NHEAD + h] + sd;
        v = v >= 0.f ? v : NEG_SLOPE * v;
        ssum += __expf(v - m);
    }
#pragma unroll
    for (int off = 32; off; off >>= 1) ssum += __shfl_xor(ssum, off);
    const float inv = 1.f / (ssum + 1e-16f);

    // phase 3: weighted accumulation, lane = channel
    float acc = __expf(self_logit - m) * inv * xt[i * HC + h * COUT + lane];
    for (int e = 0; e < deg; ++e) {
        int j = col[start + e];                  // uniform across lanes
        float v = ssrc[j * NHEAD + h] + sd;
        v = v >= 0.f ? v : NEG_SLOPE * v;
        float w = __expf(v - m) * inv;
        acc += w * xt[j * HC + h * COUT + lane];
    }
    out[i * HC + h * COUT + lane] = acc + bias[h * COUT + lane];
}

// ---------------------------------------------------------------------------
extern "C" void kernel_launch(void* const* d_in, const int* in_sizes, int n_in,
                              void* d_out, int out_size, void* d_ws, size_t ws_size,
                              hipStream_t stream) {
    const float* x       = (const float*)d_in[0];
    const int*   ei      = (const int*)d_in[1];
    const float* W       = (const float*)d_in[2];
    const float* att_src = (const float*)d_in[3];
    const float* att_dst = (const float*)d_in[4];
    const float* bias    = (const float*)d_in[5];
    float* out = (float*)d_out;

    char* ws = (char*)d_ws;
    float* xt     = (float*)(ws);                                  // 16384*512*4 = 33554432
    float* ssrc   = (float*)(ws + 33554432);                       // 16384*8*4   = 524288
    float* sdst   = (float*)(ws + 33554432 + 524288);              // 524288
    int*   cnt    = (int*)(ws + 34603008);                         // 2048*4      = 8192
    int*   rowptr = (int*)(ws + 34611200);                         // 16384*4     = 65536
    int*   widx   = (int*)(ws + 34676736);                         // 65536
    int*   col    = (int*)(ws + 34742272);                         // 262144*4    = 1048576

    hipMemsetAsync(cnt, 0, NNODE * sizeof(int), stream);

    gemm_f32<<<dim3(HC / 64, BN_TOT / 64), 256, 0, stream>>>(x, W, xt);
    att_scores<<<BN_TOT / 4, 256, 0, stream>>>(xt, att_src, att_dst, ssrc, sdst);
    count_edges<<<NEDGE / 256, 256, 0, stream>>>(ei, cnt);
    scan_rowptr<<<1, 256, 0, stream>>>(cnt, rowptr, widx);
    scatter_edges<<<(BDIM * NEDGE) / 256, 256, 0, stream>>>(ei, widx, col);
    aggregate<<<BN_TOT, 512, 0, stream>>>(xt, ssrc, sdst, cnt, rowptr, col, bias, out);
}

// Round 3
// 255.235 us; speedup vs baseline: 1.1478x; 1.1478x over previous
//
#include <hip/hip_runtime.h>
#include <hip/hip_bf16.h>

// Problem constants
#define BDIM 8
#define NNODE 2048
#define CIN 256
#define NEDGE 32768
#define NHEAD 8
#define COUT 64
#define HC 512            // NHEAD * COUT
#define BN_TOT 16384      // BDIM * NNODE
#define NEG_SLOPE 0.2f

// ---------------------------------------------------------------------------
// Kernel 1: xt = x @ W_lin   [16384,256] x [256,512] -> [16384,512], fp32
// 128x128 tile, BK=16, 256 threads, 8x8 per-thread microtile.
// Bs bank-group permutation: fragment t lives at physical 8t + 4*(t>>2).
// Max physical index = 8*15 + 4*3 + 8 = 140 -> row width MUST be >= 140
// (was 136 in round 2: fragment 15 overflowed into the next row = corruption).
// ---------------------------------------------------------------------------
__global__ __launch_bounds__(256) void gemm_f32(const float* __restrict__ A,
                                                const float* __restrict__ B,
                                                float* __restrict__ C) {
    __shared__ float As[16][132];
    __shared__ float Bs[16][140];

    const int tid  = threadIdx.x;
    const int row0 = blockIdx.y * 128;
    const int col0 = blockIdx.x * 128;
    const int tx = tid & 15;                 // 0..15 col fragment
    const int ty = tid >> 4;                 // 0..15 row fragment
    const int bcolPhys = 8 * tx + 4 * (tx >> 2);

    const int aRow = tid >> 2;               // 0..63
    const int aK   = (tid & 3) * 4;          // 0,4,8,12
    const int bK   = tid >> 4;               // 0..15
    const int bt   = tid & 15;               // 0..15
    const int bPhys = 8 * bt + 4 * (bt >> 2);

    float acc[8][8] = {};

    for (int k0 = 0; k0 < CIN; k0 += 16) {
        float4 a0 = *(const float4*)&A[(row0 + aRow) * CIN + k0 + aK];
        float4 a1 = *(const float4*)&A[(row0 + aRow + 64) * CIN + k0 + aK];
        float4 b0 = *(const float4*)&B[(k0 + bK) * HC + col0 + 8 * bt];
        float4 b1 = *(const float4*)&B[(k0 + bK) * HC + col0 + 8 * bt + 4];
        __syncthreads();
        As[aK + 0][aRow] = a0.x; As[aK + 1][aRow] = a0.y;
        As[aK + 2][aRow] = a0.z; As[aK + 3][aRow] = a0.w;
        As[aK + 0][aRow + 64] = a1.x; As[aK + 1][aRow + 64] = a1.y;
        As[aK + 2][aRow + 64] = a1.z; As[aK + 3][aRow + 64] = a1.w;
        *(float4*)&Bs[bK][bPhys]     = b0;
        *(float4*)&Bs[bK][bPhys + 4] = b1;
        __syncthreads();
#pragma unroll
        for (int k = 0; k < 16; ++k) {
            float a[8], b[8];
            *(float4*)&a[0] = *(const float4*)&As[k][ty * 8];
            *(float4*)&a[4] = *(const float4*)&As[k][ty * 8 + 4];
            *(float4*)&b[0] = *(const float4*)&Bs[k][bcolPhys];
            *(float4*)&b[4] = *(const float4*)&Bs[k][bcolPhys + 4];
#pragma unroll
            for (int i = 0; i < 8; ++i)
#pragma unroll
                for (int j = 0; j < 8; ++j) acc[i][j] += a[i] * b[j];
        }
    }
#pragma unroll
    for (int r = 0; r < 8; ++r) {
        float4 v0 = {acc[r][0], acc[r][1], acc[r][2], acc[r][3]};
        float4 v1 = {acc[r][4], acc[r][5], acc[r][6], acc[r][7]};
        *(float4*)&C[(row0 + ty * 8 + r) * HC + col0 + tx * 8]     = v0;
        *(float4*)&C[(row0 + ty * 8 + r) * HC + col0 + tx * 8 + 4] = v1;
    }
}

// ---------------------------------------------------------------------------
// Kernel 2: per-node attention scores (unchanged)
// ---------------------------------------------------------------------------
__global__ __launch_bounds__(256) void att_scores(const float* __restrict__ xt,
                                                  const float* __restrict__ att_src,
                                                  const float* __restrict__ att_dst,
                                                  float* __restrict__ ssrc,
                                                  float* __restrict__ sdst) {
    const int n = blockIdx.x * 4 + (threadIdx.x >> 6);
    const int l = threadIdx.x & 63;

    const float4* p = (const float4*)&xt[n * HC + l * 8];
    float4 v0 = p[0], v1 = p[1];
    const float4* as = (const float4*)&att_src[l * 8];
    float4 a0 = as[0], a1 = as[1];
    const float4* ad = (const float4*)&att_dst[l * 8];
    float4 b0 = ad[0], b1 = ad[1];

    float ps = v0.x * a0.x + v0.y * a0.y + v0.z * a0.z + v0.w * a0.w +
               v1.x * a1.x + v1.y * a1.y + v1.z * a1.z + v1.w * a1.w;
    float pd = v0.x * b0.x + v0.y * b0.y + v0.z * b0.z + v0.w * b0.w +
               v1.x * b1.x + v1.y * b1.y + v1.z * b1.z + v1.w * b1.w;

    ps += __shfl_xor(ps, 4); ps += __shfl_xor(ps, 2); ps += __shfl_xor(ps, 1);
    pd += __shfl_xor(pd, 4); pd += __shfl_xor(pd, 2); pd += __shfl_xor(pd, 1);

    if ((l & 7) == 0) {
        ssrc[n * NHEAD + (l >> 3)] = ps;
        sdst[n * NHEAD + (l >> 3)] = pd;
    }
}

// ---------------------------------------------------------------------------
// CSR build (unchanged)
// ---------------------------------------------------------------------------
__global__ void count_edges(const int* __restrict__ ei, int* __restrict__ cnt) {
    int t = blockIdx.x * 256 + threadIdx.x;
    atomicAdd(&cnt[ei[NEDGE + t]], 1);
}

__global__ __launch_bounds__(256) void scan_rowptr(const int* __restrict__ cnt,
                                                   int* __restrict__ rowptr,
                                                   int* __restrict__ widx) {
    __shared__ int sums[256];
    const int t = threadIdx.x;
    int v[8];
    int tot = 0;
#pragma unroll
    for (int i = 0; i < 8; ++i) { v[i] = cnt[t * 8 + i]; tot += v[i]; }
    sums[t] = tot;
    __syncthreads();
    for (int off = 1; off < 256; off <<= 1) {
        int x = (t >= off) ? sums[t - off] : 0;
        __syncthreads();
        sums[t] += x;
        __syncthreads();
    }
    int run = sums[t] - tot;
    int base[8];
#pragma unroll
    for (int i = 0; i < 8; ++i) { base[i] = run; run += v[i]; }
#pragma unroll
    for (int b = 0; b < BDIM; ++b) {
#pragma unroll
        for (int i = 0; i < 8; ++i) {
            int n = t * 8 + i;
            int val = b * NEDGE + base[i];
            rowptr[b * NNODE + n] = val;
            widx[b * NNODE + n] = val;
        }
    }
}

__global__ void scatter_edges(const int* __restrict__ ei, int* __restrict__ widx,
                              int* __restrict__ col) {
    int t = blockIdx.x * 256 + threadIdx.x;
    int b = t >> 15;
    int e = t & (NEDGE - 1);
    int s = ei[e];
    int d = ei[NEDGE + e];
    int p = atomicAdd(&widx[b * NNODE + d], 1);
    col[p] = b * NNODE + s;
}

// ---------------------------------------------------------------------------
// Kernel 3: per-node softmax + aggregation, chunk-broadcast version.
// One block per node; 8 waves = 8 heads.
//   phases 1/2: lane-parallel max / exp-sum over incoming edges.
//   phase 3: per 64-edge chunk, lane e computes (j_e, w_e) ONCE; the serial
//   channel-parallel loop broadcasts them via __shfl (uniform index ->
//   readlane). Out-of-range tail lanes carry w=0 (j=i valid) so the 8-deep
//   unrolled broadcast needs no tail guard.
// ---------------------------------------------------------------------------
__global__ __launch_bounds__(512) void aggregate(const float* __restrict__ xt,
                                                 const float* __restrict__ ssrc,
                                                 const float* __restrict__ sdst,
                                                 const int* __restrict__ cnt,
                                                 const int* __restrict__ rowptr,
                                                 const int* __restrict__ col,
                                                 const float* __restrict__ bias,
                                                 float* __restrict__ out) {
    const int i = blockIdx.x;
    const int h = threadIdx.x >> 6;
    const int lane = threadIdx.x & 63;
    const int n = i & (NNODE - 1);
    const int deg = cnt[n];
    const int start = rowptr[i];

    const float sd = sdst[i * NHEAD + h];
    float self_raw = ssrc[i * NHEAD + h] + sd;
    float self_logit = self_raw >= 0.f ? self_raw : NEG_SLOPE * self_raw;

    // phase 1: max
    float m = self_logit;
    for (int e = lane; e < deg; e += 64) {
        int j = col[start + e];
        float v = ssrc[j * NHEAD + h] + sd;
        v = v >= 0.f ? v : NEG_SLOPE * v;
        m = fmaxf(m, v);
    }
#pragma unroll
    for (int off = 32; off; off >>= 1) m = fmaxf(m, __shfl_xor(m, off));

    // phase 2: exp-sum
    float sp = 0.f;
    for (int e = lane; e < deg; e += 64) {
        int j = col[start + e];
        float v = ssrc[j * NHEAD + h] + sd;
        v = v >= 0.f ? v : NEG_SLOPE * v;
        sp += __expf(v - m);
    }
#pragma unroll
    for (int off = 32; off; off >>= 1) sp += __shfl_xor(sp, off);
    const float eself = __expf(self_logit - m);
    const float inv = 1.f / (sp + eself + 1e-16f);

    // phase 3: chunk-broadcast weighted accumulation (lane = channel)
    float a0 = eself * inv * xt[i * HC + h * COUT + lane];
    float a1 = 0.f, a2 = 0.f, a3 = 0.f;
    for (int c0 = 0; c0 < deg; c0 += 64) {
        int jv = i;
        float wv = 0.f;
        int e = c0 + lane;
        if (e < deg) {
            jv = col[start + e];
            float v = ssrc[jv * NHEAD + h] + sd;
            v = v >= 0.f ? v : NEG_SLOPE * v;
            wv = __expf(v - m) * inv;
        }
        const int cend = min(deg - c0, 64);
        for (int e0 = 0; e0 < cend; e0 += 8) {
#pragma unroll
            for (int u = 0; u < 8; ++u) {
                int j   = __shfl(jv, e0 + u);
                float w = __shfl(wv, e0 + u);
                float x = xt[j * HC + h * COUT + lane];
                if ((u & 3) == 0)      a0 += w * x;
                else if ((u & 3) == 1) a1 += w * x;
                else if ((u & 3) == 2) a2 += w * x;
                else                   a3 += w * x;
            }
        }
    }
    out[i * HC + h * COUT + lane] = (a0 + a1) + (a2 + a3) + bias[h * COUT + lane];
}

// ---------------------------------------------------------------------------
extern "C" void kernel_launch(void* const* d_in, const int* in_sizes, int n_in,
                              void* d_out, int out_size, void* d_ws, size_t ws_size,
                              hipStream_t stream) {
    const float* x       = (const float*)d_in[0];
    const int*   ei      = (const int*)d_in[1];
    const float* W       = (const float*)d_in[2];
    const float* att_src = (const float*)d_in[3];
    const float* att_dst = (const float*)d_in[4];
    const float* bias    = (const float*)d_in[5];
    float* out = (float*)d_out;

    char* ws = (char*)d_ws;
    float* xt     = (float*)(ws);                                  // 33554432 B
    float* ssrc   = (float*)(ws + 33554432);                       // 524288 B
    float* sdst   = (float*)(ws + 33554432 + 524288);              // 524288 B
    int*   cnt    = (int*)(ws + 34603008);                         // 8192 B
    int*   rowptr = (int*)(ws + 34611200);                         // 65536 B
    int*   widx   = (int*)(ws + 34676736);                         // 65536 B
    int*   col    = (int*)(ws + 34742272);                         // 1048576 B

    hipMemsetAsync(cnt, 0, NNODE * sizeof(int), stream);

    gemm_f32<<<dim3(HC / 128, BN_TOT / 128), 256, 0, stream>>>(x, W, xt);
    att_scores<<<BN_TOT / 4, 256, 0, stream>>>(xt, att_src, att_dst, ssrc, sdst);
    count_edges<<<NEDGE / 256, 256, 0, stream>>>(ei, cnt);
    scan_rowptr<<<1, 256, 0, stream>>>(cnt, rowptr, widx);
    scatter_edges<<<(BDIM * NEDGE) / 256, 256, 0, stream>>>(ei, widx, col);
    aggregate<<<BN_TOT, 512, 0, stream>>>(xt, ssrc, sdst, cnt, rowptr, col, bias, out);
}

// Round 4
// 221.984 us; speedup vs baseline: 1.3197x; 1.1498x over previous
//
#include <hip/hip_runtime.h>
#include <hip/hip_bf16.h>

// Problem constants
#define BDIM 8
#define NNODE 2048
#define CIN 256
#define NEDGE 32768
#define NHEAD 8
#define COUT 64
#define HC 512            // NHEAD * COUT
#define BN_TOT 16384      // BDIM * NNODE
#define NEG_SLOPE 0.2f

// ---------------------------------------------------------------------------
// Kernel 1: xt = x @ W_lin   [16384,256] x [256,512] -> [16384,512], fp32
// 128x128 tile, BK=16, 256 threads, 8x8 per-thread microtile.
// Bs bank-group permutation: fragment t lives at physical 8t + 4*(t>>2);
// max physical index 140 -> row width 140.
// ---------------------------------------------------------------------------
__global__ __launch_bounds__(256) void gemm_f32(const float* __restrict__ A,
                                                const float* __restrict__ B,
                                                float* __restrict__ C) {
    __shared__ float As[16][132];
    __shared__ float Bs[16][140];

    const int tid  = threadIdx.x;
    const int row0 = blockIdx.y * 128;
    const int col0 = blockIdx.x * 128;
    const int tx = tid & 15;
    const int ty = tid >> 4;
    const int bcolPhys = 8 * tx + 4 * (tx >> 2);

    const int aRow = tid >> 2;
    const int aK   = (tid & 3) * 4;
    const int bK   = tid >> 4;
    const int bt   = tid & 15;
    const int bPhys = 8 * bt + 4 * (bt >> 2);

    float acc[8][8] = {};

    for (int k0 = 0; k0 < CIN; k0 += 16) {
        float4 a0 = *(const float4*)&A[(row0 + aRow) * CIN + k0 + aK];
        float4 a1 = *(const float4*)&A[(row0 + aRow + 64) * CIN + k0 + aK];
        float4 b0 = *(const float4*)&B[(k0 + bK) * HC + col0 + 8 * bt];
        float4 b1 = *(const float4*)&B[(k0 + bK) * HC + col0 + 8 * bt + 4];
        __syncthreads();
        As[aK + 0][aRow] = a0.x; As[aK + 1][aRow] = a0.y;
        As[aK + 2][aRow] = a0.z; As[aK + 3][aRow] = a0.w;
        As[aK + 0][aRow + 64] = a1.x; As[aK + 1][aRow + 64] = a1.y;
        As[aK + 2][aRow + 64] = a1.z; As[aK + 3][aRow + 64] = a1.w;
        *(float4*)&Bs[bK][bPhys]     = b0;
        *(float4*)&Bs[bK][bPhys + 4] = b1;
        __syncthreads();
#pragma unroll
        for (int k = 0; k < 16; ++k) {
            float a[8], b[8];
            *(float4*)&a[0] = *(const float4*)&As[k][ty * 8];
            *(float4*)&a[4] = *(const float4*)&As[k][ty * 8 + 4];
            *(float4*)&b[0] = *(const float4*)&Bs[k][bcolPhys];
            *(float4*)&b[4] = *(const float4*)&Bs[k][bcolPhys + 4];
#pragma unroll
            for (int i = 0; i < 8; ++i)
#pragma unroll
                for (int j = 0; j < 8; ++j) acc[i][j] += a[i] * b[j];
        }
    }
#pragma unroll
    for (int r = 0; r < 8; ++r) {
        float4 v0 = {acc[r][0], acc[r][1], acc[r][2], acc[r][3]};
        float4 v1 = {acc[r][4], acc[r][5], acc[r][6], acc[r][7]};
        *(float4*)&C[(row0 + ty * 8 + r) * HC + col0 + tx * 8]     = v0;
        *(float4*)&C[(row0 + ty * 8 + r) * HC + col0 + tx * 8 + 4] = v1;
    }
}

// ---------------------------------------------------------------------------
// Kernel 2: per-node attention scores (unchanged)
// ---------------------------------------------------------------------------
__global__ __launch_bounds__(256) void att_scores(const float* __restrict__ xt,
                                                  const float* __restrict__ att_src,
                                                  const float* __restrict__ att_dst,
                                                  float* __restrict__ ssrc,
                                                  float* __restrict__ sdst) {
    const int n = blockIdx.x * 4 + (threadIdx.x >> 6);
    const int l = threadIdx.x & 63;

    const float4* p = (const float4*)&xt[n * HC + l * 8];
    float4 v0 = p[0], v1 = p[1];
    const float4* as = (const float4*)&att_src[l * 8];
    float4 a0 = as[0], a1 = as[1];
    const float4* ad = (const float4*)&att_dst[l * 8];
    float4 b0 = ad[0], b1 = ad[1];

    float ps = v0.x * a0.x + v0.y * a0.y + v0.z * a0.z + v0.w * a0.w +
               v1.x * a1.x + v1.y * a1.y + v1.z * a1.z + v1.w * a1.w;
    float pd = v0.x * b0.x + v0.y * b0.y + v0.z * b0.z + v0.w * b0.w +
               v1.x * b1.x + v1.y * b1.y + v1.z * b1.z + v1.w * b1.w;

    ps += __shfl_xor(ps, 4); ps += __shfl_xor(ps, 2); ps += __shfl_xor(ps, 1);
    pd += __shfl_xor(pd, 4); pd += __shfl_xor(pd, 2); pd += __shfl_xor(pd, 1);

    if ((l & 7) == 0) {
        ssrc[n * NHEAD + (l >> 3)] = ps;
        sdst[n * NHEAD + (l >> 3)] = pd;
    }
}

// ---------------------------------------------------------------------------
// CSR build (unchanged)
// ---------------------------------------------------------------------------
__global__ void count_edges(const int* __restrict__ ei, int* __restrict__ cnt) {
    int t = blockIdx.x * 256 + threadIdx.x;
    atomicAdd(&cnt[ei[NEDGE + t]], 1);
}

__global__ __launch_bounds__(256) void scan_rowptr(const int* __restrict__ cnt,
                                                   int* __restrict__ rowptr,
                                                   int* __restrict__ widx) {
    __shared__ int sums[256];
    const int t = threadIdx.x;
    int v[8];
    int tot = 0;
#pragma unroll
    for (int i = 0; i < 8; ++i) { v[i] = cnt[t * 8 + i]; tot += v[i]; }
    sums[t] = tot;
    __syncthreads();
    for (int off = 1; off < 256; off <<= 1) {
        int x = (t >= off) ? sums[t - off] : 0;
        __syncthreads();
        sums[t] += x;
        __syncthreads();
    }
    int run = sums[t] - tot;
    int base[8];
#pragma unroll
    for (int i = 0; i < 8; ++i) { base[i] = run; run += v[i]; }
#pragma unroll
    for (int b = 0; b < BDIM; ++b) {
#pragma unroll
        for (int i = 0; i < 8; ++i) {
            int n = t * 8 + i;
            int val = b * NEDGE + base[i];
            rowptr[b * NNODE + n] = val;
            widx[b * NNODE + n] = val;
        }
    }
}

__global__ void scatter_edges(const int* __restrict__ ei, int* __restrict__ widx,
                              int* __restrict__ col) {
    int t = blockIdx.x * 256 + threadIdx.x;
    int b = t >> 15;
    int e = t & (NEDGE - 1);
    int s = ei[e];
    int d = ei[NEDGE + e];
    int p = atomicAdd(&widx[b * NNODE + d], 1);
    col[p] = b * NNODE + s;
}

// ---------------------------------------------------------------------------
// Kernel 3: merged-head aggregation. ONE wave per node handles all 8 heads.
//   Pass A/B: lane = (head = l>>3, edge-slot = l&7); logits->LDS, max & exp-sum
//   reduced over 8-lane groups. Weights stored UNNORMALIZED in wave-private
//   LDS (wlds[nb][h][68]; stride 68 => max 2-way bank alias = free; slots
//   >= deg pre-zeroed so phase-3 padding is harmless).
//   Phase 3: lane covers channels c=4l and 256+4l (heads l>>4, 4+(l>>4));
//   per edge: scalar col read (uniform addr), 2x global dwordx4 = all 512
//   channels, weights via ds_read_b128 (4 edges/read). inv folded at end.
//   No __syncthreads: LDS slice is wave-private.
//   deg>64 fallback recomputes weights on the fly (correctness guard).
// ---------------------------------------------------------------------------
__global__ __launch_bounds__(256) void aggregate(const float* __restrict__ xt,
                                                 const float* __restrict__ ssrc,
                                                 const float* __restrict__ sdst,
                                                 const int* __restrict__ cnt,
                                                 const int* __restrict__ rowptr,
                                                 const int* __restrict__ col,
                                                 const float* __restrict__ bias,
                                                 float* __restrict__ out) {
    __shared__ float wlds[4][NHEAD][68];
    const int nb   = threadIdx.x >> 6;
    const int lane = threadIdx.x & 63;
    const int i    = blockIdx.x * 4 + nb;
    const int n    = i & (NNODE - 1);
    const int deg  = cnt[n];
    const int start = rowptr[i];
    const int h    = lane >> 3;
    const int sub  = lane & 7;
    float* wrow = &wlds[nb][0][0];   // 544 floats, private to this wave

    for (int t = lane; t < NHEAD * 68; t += 64) wrow[t] = 0.f;

    const float sdh = sdst[i * NHEAD + h];
    float selfv = ssrc[i * NHEAD + h] + sdh;
    selfv = selfv >= 0.f ? selfv : NEG_SLOPE * selfv;

    // pass A: logits -> LDS, running max
    float m = selfv;
    for (int e = sub; e < deg; e += 8) {
        int j = col[start + e];
        float v = ssrc[j * NHEAD + h] + sdh;
        v = v >= 0.f ? v : NEG_SLOPE * v;
        if (e < 64) wrow[h * 68 + e] = v;
        m = fmaxf(m, v);
    }
    m = fmaxf(m, __shfl_xor(m, 4));
    m = fmaxf(m, __shfl_xor(m, 2));
    m = fmaxf(m, __shfl_xor(m, 1));

    // pass B: exp, sum; overwrite LDS with unnormalized weights
    float sp = 0.f;
    for (int e = sub; e < deg; e += 8) {
        float v;
        if (e < 64) {
            v = wrow[h * 68 + e];
        } else {
            int j = col[start + e];
            v = ssrc[j * NHEAD + h] + sdh;
            v = v >= 0.f ? v : NEG_SLOPE * v;
        }
        float w = __expf(v - m);
        if (e < 64) wrow[h * 68 + e] = w;
        sp += w;
    }
    sp += __shfl_xor(sp, 4); sp += __shfl_xor(sp, 2); sp += __shfl_xor(sp, 1);
    const float eself = __expf(selfv - m);
    const float inv = 1.f / (sp + eself + 1e-16f);

    // per-lane head context for phase 3
    const int hq0 = lane >> 4;       // head for channels [0,256)
    const int hq1 = 4 + hq0;         // head for channels [256,512)
    const float inv0 = __shfl(inv, hq0 * 8), inv1 = __shfl(inv, hq1 * 8);
    const float es0  = __shfl(eself, hq0 * 8), es1 = __shfl(eself, hq1 * 8);
    const float mm0  = __shfl(m, hq0 * 8),   mm1 = __shfl(m, hq1 * 8);
    const float sd0  = __shfl(sdh, hq0 * 8), sd1 = __shfl(sdh, hq1 * 8);

    const int c = lane * 4;
    float4 acc0 = {0.f, 0.f, 0.f, 0.f};
    float4 acc1 = {0.f, 0.f, 0.f, 0.f};

    const int degc = min(deg, 64);
    const int deg4 = (degc + 3) & ~3;
    for (int e0 = 0; e0 < deg4; e0 += 4) {
        float4 w0 = *(const float4*)&wrow[hq0 * 68 + e0];
        float4 w1 = *(const float4*)&wrow[hq1 * 68 + e0];
#pragma unroll
        for (int u = 0; u < 4; ++u) {
            int ec = min(e0 + u, deg - 1);     // pad edges: w=0, clamp keeps j valid
            int j = col[start + ec];
            const float4 x0 = *(const float4*)&xt[j * HC + c];
            const float4 x1 = *(const float4*)&xt[j * HC + 256 + c];
            float wa = (&w0.x)[u], wb = (&w1.x)[u];
            acc0.x += wa * x0.x; acc0.y += wa * x0.y;
            acc0.z += wa * x0.z; acc0.w += wa * x0.w;
            acc1.x += wb * x1.x; acc1.y += wb * x1.y;
            acc1.z += wb * x1.z; acc1.w += wb * x1.w;
        }
    }
    // correctness fallback for deg > 64 (astronomically rare)
    for (int e = 64; e < deg; ++e) {
        int j = col[start + e];
        float v0 = ssrc[j * NHEAD + hq0] + sd0; v0 = v0 >= 0.f ? v0 : NEG_SLOPE * v0;
        float v1 = ssrc[j * NHEAD + hq1] + sd1; v1 = v1 >= 0.f ? v1 : NEG_SLOPE * v1;
        float wa = __expf(v0 - mm0), wb = __expf(v1 - mm1);
        const float4 x0 = *(const float4*)&xt[j * HC + c];
        const float4 x1 = *(const float4*)&xt[j * HC + 256 + c];
        acc0.x += wa * x0.x; acc0.y += wa * x0.y;
        acc0.z += wa * x0.z; acc0.w += wa * x0.w;
        acc1.x += wb * x1.x; acc1.y += wb * x1.y;
        acc1.z += wb * x1.z; acc1.w += wb * x1.w;
    }
    // self-loop term
    {
        const float4 x0 = *(const float4*)&xt[i * HC + c];
        const float4 x1 = *(const float4*)&xt[i * HC + 256 + c];
        acc0.x += es0 * x0.x; acc0.y += es0 * x0.y;
        acc0.z += es0 * x0.z; acc0.w += es0 * x0.w;
        acc1.x += es1 * x1.x; acc1.y += es1 * x1.y;
        acc1.z += es1 * x1.z; acc1.w += es1 * x1.w;
    }
    const float4 b0 = *(const float4*)&bias[c];
    const float4 b1 = *(const float4*)&bias[256 + c];
    float4 o0 = {acc0.x * inv0 + b0.x, acc0.y * inv0 + b0.y,
                 acc0.z * inv0 + b0.z, acc0.w * inv0 + b0.w};
    float4 o1 = {acc1.x * inv1 + b1.x, acc1.y * inv1 + b1.y,
                 acc1.z * inv1 + b1.z, acc1.w * inv1 + b1.w};
    *(float4*)&out[i * HC + c]       = o0;
    *(float4*)&out[i * HC + 256 + c] = o1;
}

// ---------------------------------------------------------------------------
extern "C" void kernel_launch(void* const* d_in, const int* in_sizes, int n_in,
                              void* d_out, int out_size, void* d_ws, size_t ws_size,
                              hipStream_t stream) {
    const float* x       = (const float*)d_in[0];
    const int*   ei      = (const int*)d_in[1];
    const float* W       = (const float*)d_in[2];
    const float* att_src = (const float*)d_in[3];
    const float* att_dst = (const float*)d_in[4];
    const float* bias    = (const float*)d_in[5];
    float* out = (float*)d_out;

    char* ws = (char*)d_ws;
    float* xt     = (float*)(ws);                                  // 33554432 B
    float* ssrc   = (float*)(ws + 33554432);                       // 524288 B
    float* sdst   = (float*)(ws + 33554432 + 524288);              // 524288 B
    int*   cnt    = (int*)(ws + 34603008);                         // 8192 B
    int*   rowptr = (int*)(ws + 34611200);                         // 65536 B
    int*   widx   = (int*)(ws + 34676736);                         // 65536 B
    int*   col    = (int*)(ws + 34742272);                         // 1048576 B

    hipMemsetAsync(cnt, 0, NNODE * sizeof(int), stream);

    gemm_f32<<<dim3(HC / 128, BN_TOT / 128), 256, 0, stream>>>(x, W, xt);
    att_scores<<<BN_TOT / 4, 256, 0, stream>>>(xt, att_src, att_dst, ssrc, sdst);
    count_edges<<<NEDGE / 256, 256, 0, stream>>>(ei, cnt);
    scan_rowptr<<<1, 256, 0, stream>>>(cnt, rowptr, widx);
    scatter_edges<<<(BDIM * NEDGE) / 256, 256, 0, stream>>>(ei, widx, col);
    aggregate<<<BN_TOT / 4, 256, 0, stream>>>(xt, ssrc, sdst, cnt, rowptr, col, bias, out);
}

// Round 5
// 184.404 us; speedup vs baseline: 1.5887x; 1.2038x over previous
//
#include <hip/hip_runtime.h>
#include <hip/hip_bf16.h>

// Problem constants
#define BDIM 8
#define NNODE 2048
#define CIN 256
#define NEDGE 32768
#define NHEAD 8
#define COUT 64
#define HC 512            // NHEAD * COUT
#define BN_TOT 16384      // BDIM * NNODE
#define NEG_SLOPE 0.2f

typedef __hip_bfloat16 bf16;
typedef __attribute__((ext_vector_type(8))) short bfrag;   // 8 bf16 = 4 VGPRs
typedef __attribute__((ext_vector_type(4))) float ffrag;   // 4 fp32 acc

static __device__ __forceinline__ short f2b(float f) {
    __hip_bfloat16 h = __float2bfloat16(f);
    return *(short*)&h;
}

// ---------------------------------------------------------------------------
// Kernel 0: convert x -> xbf (bf16) and W[256][512] -> WT bf16 [512][256].
// Blocks 0..127: tiled transpose of W (32x32 tiles via LDS, coalesced both
// sides). Blocks 128..2175: grid-stride bf16 conversion of x (8 elems/thread).
// ---------------------------------------------------------------------------
__global__ __launch_bounds__(256) void cvt_kernel(const float* __restrict__ x,
                                                  const float* __restrict__ W,
                                                  short* __restrict__ xbf,
                                                  short* __restrict__ WT) {
    const int b = blockIdx.x;
    if (b < 128) {
        __shared__ float t[32][33];
        const int kt = b >> 4;                 // 0..7   (K tiles)
        const int nt = b & 15;                 // 0..15  (N tiles)
        const int tx = threadIdx.x & 31, ty = threadIdx.x >> 5;
#pragma unroll
        for (int i = 0; i < 4; ++i)
            t[ty + 8 * i][tx] = W[(kt * 32 + ty + 8 * i) * HC + nt * 32 + tx];
        __syncthreads();
#pragma unroll
        for (int i = 0; i < 4; ++i)
            WT[(nt * 32 + ty + 8 * i) * CIN + kt * 32 + tx] = f2b(t[tx][ty + 8 * i]);
    } else {
        const int t = (b - 128) * 256 + threadIdx.x;        // 0..524287
        const float4* px = (const float4*)x;
        float4 v0 = px[t * 2], v1 = px[t * 2 + 1];
        bfrag o;
        o[0] = f2b(v0.x); o[1] = f2b(v0.y); o[2] = f2b(v0.z); o[3] = f2b(v0.w);
        o[4] = f2b(v1.x); o[5] = f2b(v1.y); o[6] = f2b(v1.z); o[7] = f2b(v1.w);
        *(bfrag*)&xbf[t * 8] = o;
    }
}

// ---------------------------------------------------------------------------
// Kernel 1: xt = x @ W_lin via bf16 MFMA (fp32 accumulate).
// 128x128 tile, BK=32, 256 threads = 4 waves, each wave a 64x64 quadrant
// (4x4 tiles of 16x16x32). LDS rows padded to 40 shorts = 80 B = 20 banks:
// frag ds_read_b128 per quarter-wave covers all 32 banks exactly 2x (free).
// A-frag: lane holds A[m=lane&15][k=quad*8+j]; B from WT so B-frag is the
// same k-contiguous read; C/D: col=lane&15, row=quad*4+reg (m89/m91 layout).
// ---------------------------------------------------------------------------
__global__ __launch_bounds__(256) void gemm_mfma(const short* __restrict__ xbf,
                                                 const short* __restrict__ WT,
                                                 float* __restrict__ C) {
    __shared__ __align__(16) short As[128][40];
    __shared__ __align__(16) short Bs[128][40];

    const int tid  = threadIdx.x;
    const int row0 = blockIdx.y * 128;
    const int col0 = blockIdx.x * 128;
    const int w    = tid >> 6;
    const int lane = tid & 63;
    const int wm   = (w & 1) * 64;
    const int wn   = (w >> 1) * 64;
    const int fm   = lane & 15;         // frag row/col within 16
    const int fq   = lane >> 4;         // quad

    const int sr = tid >> 2;            // staging row 0..63
    const int sc = (tid & 3) * 8;       // staging k-offset (elements)

    ffrag acc[4][4] = {};

    for (int k0 = 0; k0 < CIN; k0 += 32) {
        bfrag a0 = *(const bfrag*)&xbf[(row0 + sr) * CIN + k0 + sc];
        bfrag a1 = *(const bfrag*)&xbf[(row0 + sr + 64) * CIN + k0 + sc];
        bfrag b0 = *(const bfrag*)&WT[(col0 + sr) * CIN + k0 + sc];
        bfrag b1 = *(const bfrag*)&WT[(col0 + sr + 64) * CIN + k0 + sc];
        __syncthreads();
        *(bfrag*)&As[sr][sc]      = a0;
        *(bfrag*)&As[sr + 64][sc] = a1;
        *(bfrag*)&Bs[sr][sc]      = b0;
        *(bfrag*)&Bs[sr + 64][sc] = b1;
        __syncthreads();

        bfrag af[4], bfr[4];
#pragma unroll
        for (int g = 0; g < 4; ++g) {
            af[g]  = *(const bfrag*)&As[wm + g * 16 + fm][fq * 8];
            bfr[g] = *(const bfrag*)&Bs[wn + g * 16 + fm][fq * 8];
        }
#pragma unroll
        for (int mg = 0; mg < 4; ++mg)
#pragma unroll
            for (int ng = 0; ng < 4; ++ng)
                acc[mg][ng] = __builtin_amdgcn_mfma_f32_16x16x32_bf16(
                    af[mg], bfr[ng], acc[mg][ng], 0, 0, 0);
    }

#pragma unroll
    for (int mg = 0; mg < 4; ++mg)
#pragma unroll
        for (int ng = 0; ng < 4; ++ng) {
            const int rbase = row0 + wm + mg * 16 + fq * 4;
            const int c     = col0 + wn + ng * 16 + fm;
#pragma unroll
            for (int r = 0; r < 4; ++r)
                C[(rbase + r) * HC + c] = acc[mg][ng][r];
        }
}

// ---------------------------------------------------------------------------
// Kernel 2: per-node attention scores (unchanged)
// ---------------------------------------------------------------------------
__global__ __launch_bounds__(256) void att_scores(const float* __restrict__ xt,
                                                  const float* __restrict__ att_src,
                                                  const float* __restrict__ att_dst,
                                                  float* __restrict__ ssrc,
                                                  float* __restrict__ sdst) {
    const int n = blockIdx.x * 4 + (threadIdx.x >> 6);
    const int l = threadIdx.x & 63;

    const float4* p = (const float4*)&xt[n * HC + l * 8];
    float4 v0 = p[0], v1 = p[1];
    const float4* as = (const float4*)&att_src[l * 8];
    float4 a0 = as[0], a1 = as[1];
    const float4* ad = (const float4*)&att_dst[l * 8];
    float4 b0 = ad[0], b1 = ad[1];

    float ps = v0.x * a0.x + v0.y * a0.y + v0.z * a0.z + v0.w * a0.w +
               v1.x * a1.x + v1.y * a1.y + v1.z * a1.z + v1.w * a1.w;
    float pd = v0.x * b0.x + v0.y * b0.y + v0.z * b0.z + v0.w * b0.w +
               v1.x * b1.x + v1.y * b1.y + v1.z * b1.z + v1.w * b1.w;

    ps += __shfl_xor(ps, 4); ps += __shfl_xor(ps, 2); ps += __shfl_xor(ps, 1);
    pd += __shfl_xor(pd, 4); pd += __shfl_xor(pd, 2); pd += __shfl_xor(pd, 1);

    if ((l & 7) == 0) {
        ssrc[n * NHEAD + (l >> 3)] = ps;
        sdst[n * NHEAD + (l >> 3)] = pd;
    }
}

// ---------------------------------------------------------------------------
// CSR build (unchanged)
// ---------------------------------------------------------------------------
__global__ void count_edges(const int* __restrict__ ei, int* __restrict__ cnt) {
    int t = blockIdx.x * 256 + threadIdx.x;
    atomicAdd(&cnt[ei[NEDGE + t]], 1);
}

__global__ __launch_bounds__(256) void scan_rowptr(const int* __restrict__ cnt,
                                                   int* __restrict__ rowptr,
                                                   int* __restrict__ widx) {
    __shared__ int sums[256];
    const int t = threadIdx.x;
    int v[8];
    int tot = 0;
#pragma unroll
    for (int i = 0; i < 8; ++i) { v[i] = cnt[t * 8 + i]; tot += v[i]; }
    sums[t] = tot;
    __syncthreads();
    for (int off = 1; off < 256; off <<= 1) {
        int x = (t >= off) ? sums[t - off] : 0;
        __syncthreads();
        sums[t] += x;
        __syncthreads();
    }
    int run = sums[t] - tot;
    int base[8];
#pragma unroll
    for (int i = 0; i < 8; ++i) { base[i] = run; run += v[i]; }
#pragma unroll
    for (int b = 0; b < BDIM; ++b) {
#pragma unroll
        for (int i = 0; i < 8; ++i) {
            int n = t * 8 + i;
            int val = b * NEDGE + base[i];
            rowptr[b * NNODE + n] = val;
            widx[b * NNODE + n] = val;
        }
    }
}

__global__ void scatter_edges(const int* __restrict__ ei, int* __restrict__ widx,
                              int* __restrict__ col) {
    int t = blockIdx.x * 256 + threadIdx.x;
    int b = t >> 15;
    int e = t & (NEDGE - 1);
    int s = ei[e];
    int d = ei[NEDGE + e];
    int p = atomicAdd(&widx[b * NNODE + d], 1);
    col[p] = b * NNODE + s;
}

// ---------------------------------------------------------------------------
// Kernel 3: merged-head aggregation (unchanged from round 4)
// ---------------------------------------------------------------------------
__global__ __launch_bounds__(256) void aggregate(const float* __restrict__ xt,
                                                 const float* __restrict__ ssrc,
                                                 const float* __restrict__ sdst,
                                                 const int* __restrict__ cnt,
                                                 const int* __restrict__ rowptr,
                                                 const int* __restrict__ col,
                                                 const float* __restrict__ bias,
                                                 float* __restrict__ out) {
    __shared__ float wlds[4][NHEAD][68];
    const int nb   = threadIdx.x >> 6;
    const int lane = threadIdx.x & 63;
    const int i    = blockIdx.x * 4 + nb;
    const int n    = i & (NNODE - 1);
    const int deg  = cnt[n];
    const int start = rowptr[i];
    const int h    = lane >> 3;
    const int sub  = lane & 7;
    float* wrow = &wlds[nb][0][0];

    for (int t = lane; t < NHEAD * 68; t += 64) wrow[t] = 0.f;

    const float sdh = sdst[i * NHEAD + h];
    float selfv = ssrc[i * NHEAD + h] + sdh;
    selfv = selfv >= 0.f ? selfv : NEG_SLOPE * selfv;

    float m = selfv;
    for (int e = sub; e < deg; e += 8) {
        int j = col[start + e];
        float v = ssrc[j * NHEAD + h] + sdh;
        v = v >= 0.f ? v : NEG_SLOPE * v;
        if (e < 64) wrow[h * 68 + e] = v;
        m = fmaxf(m, v);
    }
    m = fmaxf(m, __shfl_xor(m, 4));
    m = fmaxf(m, __shfl_xor(m, 2));
    m = fmaxf(m, __shfl_xor(m, 1));

    float sp = 0.f;
    for (int e = sub; e < deg; e += 8) {
        float v;
        if (e < 64) {
            v = wrow[h * 68 + e];
        } else {
            int j = col[start + e];
            v = ssrc[j * NHEAD + h] + sdh;
            v = v >= 0.f ? v : NEG_SLOPE * v;
        }
        float w = __expf(v - m);
        if (e < 64) wrow[h * 68 + e] = w;
        sp += w;
    }
    sp += __shfl_xor(sp, 4); sp += __shfl_xor(sp, 2); sp += __shfl_xor(sp, 1);
    const float eself = __expf(selfv - m);
    const float inv = 1.f / (sp + eself + 1e-16f);

    const int hq0 = lane >> 4;
    const int hq1 = 4 + hq0;
    const float inv0 = __shfl(inv, hq0 * 8), inv1 = __shfl(inv, hq1 * 8);
    const float es0  = __shfl(eself, hq0 * 8), es1 = __shfl(eself, hq1 * 8);
    const float mm0  = __shfl(m, hq0 * 8),   mm1 = __shfl(m, hq1 * 8);
    const float sd0  = __shfl(sdh, hq0 * 8), sd1 = __shfl(sdh, hq1 * 8);

    const int c = lane * 4;
    float4 acc0 = {0.f, 0.f, 0.f, 0.f};
    float4 acc1 = {0.f, 0.f, 0.f, 0.f};

    const int degc = min(deg, 64);
    const int deg4 = (degc + 3) & ~3;
    for (int e0 = 0; e0 < deg4; e0 += 4) {
        float4 w0 = *(const float4*)&wrow[hq0 * 68 + e0];
        float4 w1 = *(const float4*)&wrow[hq1 * 68 + e0];
#pragma unroll
        for (int u = 0; u < 4; ++u) {
            int ec = min(e0 + u, deg - 1);
            int j = col[start + ec];
            const float4 x0 = *(const float4*)&xt[j * HC + c];
            const float4 x1 = *(const float4*)&xt[j * HC + 256 + c];
            float wa = (&w0.x)[u], wb = (&w1.x)[u];
            acc0.x += wa * x0.x; acc0.y += wa * x0.y;
            acc0.z += wa * x0.z; acc0.w += wa * x0.w;
            acc1.x += wb * x1.x; acc1.y += wb * x1.y;
            acc1.z += wb * x1.z; acc1.w += wb * x1.w;
        }
    }
    for (int e = 64; e < deg; ++e) {
        int j = col[start + e];
        float v0 = ssrc[j * NHEAD + hq0] + sd0; v0 = v0 >= 0.f ? v0 : NEG_SLOPE * v0;
        float v1 = ssrc[j * NHEAD + hq1] + sd1; v1 = v1 >= 0.f ? v1 : NEG_SLOPE * v1;
        float wa = __expf(v0 - mm0), wb = __expf(v1 - mm1);
        const float4 x0 = *(const float4*)&xt[j * HC + c];
        const float4 x1 = *(const float4*)&xt[j * HC + 256 + c];
        acc0.x += wa * x0.x; acc0.y += wa * x0.y;
        acc0.z += wa * x0.z; acc0.w += wa * x0.w;
        acc1.x += wb * x1.x; acc1.y += wb * x1.y;
        acc1.z += wb * x1.z; acc1.w += wb * x1.w;
    }
    {
        const float4 x0 = *(const float4*)&xt[i * HC + c];
        const float4 x1 = *(const float4*)&xt[i * HC + 256 + c];
        acc0.x += es0 * x0.x; acc0.y += es0 * x0.y;
        acc0.z += es0 * x0.z; acc0.w += es0 * x0.w;
        acc1.x += es1 * x1.x; acc1.y += es1 * x1.y;
        acc1.z += es1 * x1.z; acc1.w += es1 * x1.w;
    }
    const float4 b0 = *(const float4*)&bias[c];
    const float4 b1 = *(const float4*)&bias[256 + c];
    float4 o0 = {acc0.x * inv0 + b0.x, acc0.y * inv0 + b0.y,
                 acc0.z * inv0 + b0.z, acc0.w * inv0 + b0.w};
    float4 o1 = {acc1.x * inv1 + b1.x, acc1.y * inv1 + b1.y,
                 acc1.z * inv1 + b1.z, acc1.w * inv1 + b1.w};
    *(float4*)&out[i * HC + c]       = o0;
    *(float4*)&out[i * HC + 256 + c] = o1;
}

// ---------------------------------------------------------------------------
extern "C" void kernel_launch(void* const* d_in, const int* in_sizes, int n_in,
                              void* d_out, int out_size, void* d_ws, size_t ws_size,
                              hipStream_t stream) {
    const float* x       = (const float*)d_in[0];
    const int*   ei      = (const int*)d_in[1];
    const float* W       = (const float*)d_in[2];
    const float* att_src = (const float*)d_in[3];
    const float* att_dst = (const float*)d_in[4];
    const float* bias    = (const float*)d_in[5];
    float* out = (float*)d_out;

    char* ws = (char*)d_ws;
    float* xt     = (float*)(ws);                                  // 33554432 B
    float* ssrc   = (float*)(ws + 33554432);                       // 524288 B
    float* sdst   = (float*)(ws + 33554432 + 524288);              // 524288 B
    int*   cnt    = (int*)(ws + 34603008);                         // 8192 B
    int*   rowptr = (int*)(ws + 34611200);                         // 65536 B
    int*   widx   = (int*)(ws + 34676736);                         // 65536 B
    int*   col    = (int*)(ws + 34742272);                         // 1048576 B
    short* xbf    = (short*)(ws + 35790848);                       // 8388608 B
    short* WT     = (short*)(ws + 44179456);                       // 262144 B
                                                                   // total 44441600 B
    hipMemsetAsync(cnt, 0, NNODE * sizeof(int), stream);

    cvt_kernel<<<128 + 2048, 256, 0, stream>>>(x, W, xbf, WT);
    gemm_mfma<<<dim3(HC / 128, BN_TOT / 128), 256, 0, stream>>>(xbf, WT, xt);
    att_scores<<<BN_TOT / 4, 256, 0, stream>>>(xt, att_src, att_dst, ssrc, sdst);
    count_edges<<<NEDGE / 256, 256, 0, stream>>>(ei, cnt);
    scan_rowptr<<<1, 256, 0, stream>>>(cnt, rowptr, widx);
    scatter_edges<<<(BDIM * NEDGE) / 256, 256, 0, stream>>>(ei, widx, col);
    aggregate<<<BN_TOT / 4, 256, 0, stream>>>(xt, ssrc, sdst, cnt, rowptr, col, bias, out);
}

// Round 6
// 146.983 us; speedup vs baseline: 1.9931x; 1.2546x over previous
//
#include <hip/hip_runtime.h>
#include <hip/hip_bf16.h>

// Problem constants
#define BDIM 8
#define NNODE 2048
#define CIN 256
#define NEDGE 32768
#define NHEAD 8
#define COUT 64
#define HC 512            // NHEAD * COUT
#define BN_TOT 16384      // BDIM * NNODE
#define NEG_SLOPE 0.2f

typedef __hip_bfloat16 bf16;
typedef __attribute__((ext_vector_type(8))) short bfrag;   // 8 bf16 = 4 VGPRs
typedef __attribute__((ext_vector_type(4))) float ffrag;   // 4 fp32 acc

static __device__ __forceinline__ short f2b(float f) {
    __hip_bfloat16 h = __float2bfloat16(f);
    return *(short*)&h;
}
static __device__ __forceinline__ float b2f(short s) {
    return __uint_as_float(((unsigned)(unsigned short)s) << 16);
}

// ---------------------------------------------------------------------------
// Kernel 0: convert x -> xbf (bf16) and W[256][512] -> WT bf16 [512][256].
// ---------------------------------------------------------------------------
__global__ __launch_bounds__(256) void cvt_kernel(const float* __restrict__ x,
                                                  const float* __restrict__ W,
                                                  short* __restrict__ xbf,
                                                  short* __restrict__ WT) {
    const int b = blockIdx.x;
    if (b < 128) {
        __shared__ float t[32][33];
        const int kt = b >> 4;
        const int nt = b & 15;
        const int tx = threadIdx.x & 31, ty = threadIdx.x >> 5;
#pragma unroll
        for (int i = 0; i < 4; ++i)
            t[ty + 8 * i][tx] = W[(kt * 32 + ty + 8 * i) * HC + nt * 32 + tx];
        __syncthreads();
#pragma unroll
        for (int i = 0; i < 4; ++i)
            WT[(nt * 32 + ty + 8 * i) * CIN + kt * 32 + tx] = f2b(t[tx][ty + 8 * i]);
    } else {
        const int t = (b - 128) * 256 + threadIdx.x;
        const float4* px = (const float4*)x;
        float4 v0 = px[t * 2], v1 = px[t * 2 + 1];
        bfrag o;
        o[0] = f2b(v0.x); o[1] = f2b(v0.y); o[2] = f2b(v0.z); o[3] = f2b(v0.w);
        o[4] = f2b(v1.x); o[5] = f2b(v1.y); o[6] = f2b(v1.z); o[7] = f2b(v1.w);
        *(bfrag*)&xbf[t * 8] = o;
    }
}

// ---------------------------------------------------------------------------
// Kernel 1: xt = x @ W_lin via bf16 MFMA; OUTPUT IS bf16 (xtb).
// 128x128 tile, BK=32, 4 waves x 64x64 quadrant. Same layout as round 5.
// fp32 xt is gone: every consumer (scores, gather, self-loop) reads xtb,
// halving all downstream traffic.
// ---------------------------------------------------------------------------
__global__ __launch_bounds__(256) void gemm_mfma(const short* __restrict__ xbf,
                                                 const short* __restrict__ WT,
                                                 short* __restrict__ xtb) {
    __shared__ __align__(16) short As[128][40];
    __shared__ __align__(16) short Bs[128][40];

    const int tid  = threadIdx.x;
    const int row0 = blockIdx.y * 128;
    const int col0 = blockIdx.x * 128;
    const int w    = tid >> 6;
    const int lane = tid & 63;
    const int wm   = (w & 1) * 64;
    const int wn   = (w >> 1) * 64;
    const int fm   = lane & 15;
    const int fq   = lane >> 4;

    const int sr = tid >> 2;
    const int sc = (tid & 3) * 8;

    ffrag acc[4][4] = {};

    for (int k0 = 0; k0 < CIN; k0 += 32) {
        bfrag a0 = *(const bfrag*)&xbf[(row0 + sr) * CIN + k0 + sc];
        bfrag a1 = *(const bfrag*)&xbf[(row0 + sr + 64) * CIN + k0 + sc];
        bfrag b0 = *(const bfrag*)&WT[(col0 + sr) * CIN + k0 + sc];
        bfrag b1 = *(const bfrag*)&WT[(col0 + sr + 64) * CIN + k0 + sc];
        __syncthreads();
        *(bfrag*)&As[sr][sc]      = a0;
        *(bfrag*)&As[sr + 64][sc] = a1;
        *(bfrag*)&Bs[sr][sc]      = b0;
        *(bfrag*)&Bs[sr + 64][sc] = b1;
        __syncthreads();

        bfrag af[4], bfr[4];
#pragma unroll
        for (int g = 0; g < 4; ++g) {
            af[g]  = *(const bfrag*)&As[wm + g * 16 + fm][fq * 8];
            bfr[g] = *(const bfrag*)&Bs[wn + g * 16 + fm][fq * 8];
        }
#pragma unroll
        for (int mg = 0; mg < 4; ++mg)
#pragma unroll
            for (int ng = 0; ng < 4; ++ng)
                acc[mg][ng] = __builtin_amdgcn_mfma_f32_16x16x32_bf16(
                    af[mg], bfr[ng], acc[mg][ng], 0, 0, 0);
    }

#pragma unroll
    for (int mg = 0; mg < 4; ++mg)
#pragma unroll
        for (int ng = 0; ng < 4; ++ng) {
            const int rbase = row0 + wm + mg * 16 + fq * 4;
            const int c     = col0 + wn + ng * 16 + fm;
#pragma unroll
            for (int r = 0; r < 4; ++r)
                xtb[(rbase + r) * HC + c] = f2b(acc[mg][ng][r]);
        }
}

// ---------------------------------------------------------------------------
// Kernel 2: per-node attention scores, reading bf16 xtb.
// Lane l covers channels 8l..8l+7 (head l>>3); 8-lane shuffle reduce.
// ---------------------------------------------------------------------------
__global__ __launch_bounds__(256) void att_scores(const short* __restrict__ xtb,
                                                  const float* __restrict__ att_src,
                                                  const float* __restrict__ att_dst,
                                                  float* __restrict__ ssrc,
                                                  float* __restrict__ sdst) {
    const int n = blockIdx.x * 4 + (threadIdx.x >> 6);
    const int l = threadIdx.x & 63;

    bfrag xv = *(const bfrag*)&xtb[n * HC + l * 8];
    const float4* as = (const float4*)&att_src[l * 8];
    float4 a0 = as[0], a1 = as[1];
    const float4* ad = (const float4*)&att_dst[l * 8];
    float4 b0 = ad[0], b1 = ad[1];

    float xf[8];
#pragma unroll
    for (int k = 0; k < 8; ++k) xf[k] = b2f(xv[k]);

    float ps = xf[0] * a0.x + xf[1] * a0.y + xf[2] * a0.z + xf[3] * a0.w +
               xf[4] * a1.x + xf[5] * a1.y + xf[6] * a1.z + xf[7] * a1.w;
    float pd = xf[0] * b0.x + xf[1] * b0.y + xf[2] * b0.z + xf[3] * b0.w +
               xf[4] * b1.x + xf[5] * b1.y + xf[6] * b1.z + xf[7] * b1.w;

    ps += __shfl_xor(ps, 4); ps += __shfl_xor(ps, 2); ps += __shfl_xor(ps, 1);
    pd += __shfl_xor(pd, 4); pd += __shfl_xor(pd, 2); pd += __shfl_xor(pd, 1);

    if ((l & 7) == 0) {
        ssrc[n * NHEAD + (l >> 3)] = ps;
        sdst[n * NHEAD + (l >> 3)] = pd;
    }
}

// ---------------------------------------------------------------------------
// CSR build (unchanged)
// ---------------------------------------------------------------------------
__global__ void count_edges(const int* __restrict__ ei, int* __restrict__ cnt) {
    int t = blockIdx.x * 256 + threadIdx.x;
    atomicAdd(&cnt[ei[NEDGE + t]], 1);
}

__global__ __launch_bounds__(256) void scan_rowptr(const int* __restrict__ cnt,
                                                   int* __restrict__ rowptr,
                                                   int* __restrict__ widx) {
    __shared__ int sums[256];
    const int t = threadIdx.x;
    int v[8];
    int tot = 0;
#pragma unroll
    for (int i = 0; i < 8; ++i) { v[i] = cnt[t * 8 + i]; tot += v[i]; }
    sums[t] = tot;
    __syncthreads();
    for (int off = 1; off < 256; off <<= 1) {
        int x = (t >= off) ? sums[t - off] : 0;
        __syncthreads();
        sums[t] += x;
        __syncthreads();
    }
    int run = sums[t] - tot;
    int base[8];
#pragma unroll
    for (int i = 0; i < 8; ++i) { base[i] = run; run += v[i]; }
#pragma unroll
    for (int b = 0; b < BDIM; ++b) {
#pragma unroll
        for (int i = 0; i < 8; ++i) {
            int n = t * 8 + i;
            int val = b * NEDGE + base[i];
            rowptr[b * NNODE + n] = val;
            widx[b * NNODE + n] = val;
        }
    }
}

__global__ void scatter_edges(const int* __restrict__ ei, int* __restrict__ widx,
                              int* __restrict__ col) {
    int t = blockIdx.x * 256 + threadIdx.x;
    int b = t >> 15;
    int e = t & (NEDGE - 1);
    int s = ei[e];
    int d = ei[NEDGE + e];
    int p = atomicAdd(&widx[b * NNODE + d], 1);
    col[p] = b * NNODE + s;
}

// ---------------------------------------------------------------------------
// Kernel 3: merged-head aggregation, bf16 gather + batch->XCD swizzle.
//   Swizzle: blk&7 selects batch -> same XCD (round-robin dispatch heuristic)
//   so each XCD's L2 holds one batch's 2 MB xtb slice.
//   Phase 3: lane l <-> channels 8l..8l+7, head l>>3 == softmax-state lane
//   grouping, so m/sp/inv/eself are already per-lane correct (no shuffles).
//   Per edge: 1 uniform col read, 1 ds_read (weight), 1 global dwordx4
//   (16 B = lane's 8 bf16 channels), 8 cvt+fma.
// ---------------------------------------------------------------------------
__global__ __launch_bounds__(256) void aggregate(const short* __restrict__ xtb,
                                                 const float* __restrict__ ssrc,
                                                 const float* __restrict__ sdst,
                                                 const int* __restrict__ cnt,
                                                 const int* __restrict__ rowptr,
                                                 const int* __restrict__ col,
                                                 const float* __restrict__ bias,
                                                 float* __restrict__ out) {
    __shared__ float wlds[4][NHEAD][68];
    const int nb   = threadIdx.x >> 6;
    const int lane = threadIdx.x & 63;
    const int blk  = blockIdx.x;
    const int i    = (blk & 7) * NNODE + (blk >> 3) * 4 + nb;   // batch->XCD swizzle
    const int n    = i & (NNODE - 1);
    const int deg  = cnt[n];
    const int start = rowptr[i];
    const int h    = lane >> 3;
    const int sub  = lane & 7;
    float* wrow = &wlds[nb][0][0];

    for (int t = lane; t < NHEAD * 68; t += 64) wrow[t] = 0.f;

    const float sdh = sdst[i * NHEAD + h];
    float selfv = ssrc[i * NHEAD + h] + sdh;
    selfv = selfv >= 0.f ? selfv : NEG_SLOPE * selfv;

    // pass A: logits -> LDS, running max
    float m = selfv;
    for (int e = sub; e < deg; e += 8) {
        int j = col[start + e];
        float v = ssrc[j * NHEAD + h] + sdh;
        v = v >= 0.f ? v : NEG_SLOPE * v;
        if (e < 64) wrow[h * 68 + e] = v;
        m = fmaxf(m, v);
    }
    m = fmaxf(m, __shfl_xor(m, 4));
    m = fmaxf(m, __shfl_xor(m, 2));
    m = fmaxf(m, __shfl_xor(m, 1));

    // pass B: exp, sum; overwrite LDS with unnormalized weights
    float sp = 0.f;
    for (int e = sub; e < deg; e += 8) {
        float v;
        if (e < 64) {
            v = wrow[h * 68 + e];
        } else {
            int j = col[start + e];
            v = ssrc[j * NHEAD + h] + sdh;
            v = v >= 0.f ? v : NEG_SLOPE * v;
        }
        float w = __expf(v - m);
        if (e < 64) wrow[h * 68 + e] = w;
        sp += w;
    }
    sp += __shfl_xor(sp, 4); sp += __shfl_xor(sp, 2); sp += __shfl_xor(sp, 1);
    const float eself = __expf(selfv - m);
    const float inv = 1.f / (sp + eself + 1e-16f);
    // m, sp, inv, eself, sdh are uniform within each 8-lane group == per-head
    // values for head h = lane>>3 — exactly the head lane l owns in phase 3.

    const int c8 = lane * 8;
    float acc[8] = {};

    // self-loop
    {
        bfrag xv = *(const bfrag*)&xtb[i * HC + c8];
#pragma unroll
        for (int k = 0; k < 8; ++k) acc[k] += eself * b2f(xv[k]);
    }

    const int degc = min(deg, 64);
    const int deg4 = (degc + 3) & ~3;
    for (int e0 = 0; e0 < deg4; e0 += 4) {
        float4 w4 = *(const float4*)&wrow[h * 68 + e0];
#pragma unroll
        for (int u = 0; u < 4; ++u) {
            int ec = min(e0 + u, deg - 1);      // pad: w=0 (LDS pre-zeroed), j valid
            int j = col[start + ec];
            bfrag xv = *(const bfrag*)&xtb[j * HC + c8];
            float wv = (&w4.x)[u];
#pragma unroll
            for (int k = 0; k < 8; ++k) acc[k] += wv * b2f(xv[k]);
        }
    }
    // correctness fallback for deg > 64
    for (int e = 64; e < deg; ++e) {
        int j = col[start + e];
        float v = ssrc[j * NHEAD + h] + sdh;
        v = v >= 0.f ? v : NEG_SLOPE * v;
        float wv = __expf(v - m);
        bfrag xv = *(const bfrag*)&xtb[j * HC + c8];
#pragma unroll
        for (int k = 0; k < 8; ++k) acc[k] += wv * b2f(xv[k]);
    }

    const float4 b0 = *(const float4*)&bias[c8];
    const float4 b1 = *(const float4*)&bias[c8 + 4];
    float4 o0 = {acc[0] * inv + b0.x, acc[1] * inv + b0.y,
                 acc[2] * inv + b0.z, acc[3] * inv + b0.w};
    float4 o1 = {acc[4] * inv + b1.x, acc[5] * inv + b1.y,
                 acc[6] * inv + b1.z, acc[7] * inv + b1.w};
    *(float4*)&out[i * HC + c8]     = o0;
    *(float4*)&out[i * HC + c8 + 4] = o1;
}

// ---------------------------------------------------------------------------
extern "C" void kernel_launch(void* const* d_in, const int* in_sizes, int n_in,
                              void* d_out, int out_size, void* d_ws, size_t ws_size,
                              hipStream_t stream) {
    const float* x       = (const float*)d_in[0];
    const int*   ei      = (const int*)d_in[1];
    const float* W       = (const float*)d_in[2];
    const float* att_src = (const float*)d_in[3];
    const float* att_dst = (const float*)d_in[4];
    const float* bias    = (const float*)d_in[5];
    float* out = (float*)d_out;

    char* ws = (char*)d_ws;
    short* xtb    = (short*)(ws);                                  // 16777216 B
    float* ssrc   = (float*)(ws + 16777216);                       // 524288 B
    float* sdst   = (float*)(ws + 17301504);                       // 524288 B
    int*   cnt    = (int*)(ws + 17825792);                         // 8192 B
    int*   rowptr = (int*)(ws + 17833984);                         // 65536 B
    int*   widx   = (int*)(ws + 17899520);                         // 65536 B
    int*   col    = (int*)(ws + 17965056);                         // 1048576 B
    short* xbf    = (short*)(ws + 19013632);                       // 8388608 B
    short* WT     = (short*)(ws + 27402240);                       // 262144 B
                                                                   // total 27664384 B
    hipMemsetAsync(cnt, 0, NNODE * sizeof(int), stream);

    cvt_kernel<<<128 + 2048, 256, 0, stream>>>(x, W, xbf, WT);
    gemm_mfma<<<dim3(HC / 128, BN_TOT / 128), 256, 0, stream>>>(xbf, WT, xtb);
    att_scores<<<BN_TOT / 4, 256, 0, stream>>>(xtb, att_src, att_dst, ssrc, sdst);
    count_edges<<<NEDGE / 256, 256, 0, stream>>>(ei, cnt);
    scan_rowptr<<<1, 256, 0, stream>>>(cnt, rowptr, widx);
    scatter_edges<<<(BDIM * NEDGE) / 256, 256, 0, stream>>>(ei, widx, col);
    aggregate<<<BN_TOT / 4, 256, 0, stream>>>(xtb, ssrc, sdst, cnt, rowptr, col, bias, out);
}